// Round 1
// 1632.486 us; speedup vs baseline: 1.1722x; 1.1722x over previous
//
#include <hip/hip_runtime.h>
#include <hip/hip_bf16.h>
#include <stdint.h>

// Problem constants
#define TT   8192      // tokens = B*S
#define DD   2048      // d_model
#define FF   5632      // ffn hidden
#define EE   8         // experts
#define RR   16        // lora rank
#define NALL 11520     // F + F + E*2R = 5632+5632+256
#define NPAIR 16384    // T * TOPK

typedef float  f32x4  __attribute__((ext_vector_type(4)));
typedef __bf16 bf16x8 __attribute__((ext_vector_type(8)));
typedef __bf16 bf16x4 __attribute__((ext_vector_type(4)));

#define AS1CAST(p) ((__attribute__((address_space(1))) void*)(p))
#define AS3CAST(p) ((__attribute__((address_space(3))) void*)(p))

// ---------------------------------------------------------------------------
// f32 -> bf16 convert (float4 vectorized, grid-stride)
// ---------------------------------------------------------------------------
__global__ __launch_bounds__(256) void cvt_f32_bf16(const float* __restrict__ src,
                                                    __bf16* __restrict__ dst, int n4) {
    int stride = gridDim.x * 256;
    for (int i = blockIdx.x * 256 + threadIdx.x; i < n4; i += stride) {
        float4 v = ((const float4*)src)[i];
        bf16x4 o = {(__bf16)v.x, (__bf16)v.y, (__bf16)v.z, (__bf16)v.w};
        ((bf16x4*)dst)[i] = o;
    }
}

// Gather-convert A1/A3 into stacked rows [256][D]: row j=e*32+l, l<16 -> A1[e][l], else A3[e][l-16]
__global__ __launch_bounds__(256) void cvt_A13(const float* __restrict__ A1,
                                               const float* __restrict__ A3,
                                               __bf16* __restrict__ dst) {
    int i = blockIdx.x * 256 + threadIdx.x;   // [0, 256*512)
    int col4 = i & 511;                       // D/4 = 512
    int j = i >> 9;                           // row 0..255
    int e = j >> 5, l = j & 31;
    const float* src = (l < 16) ? (A1 + (size_t)(e * 16 + l) * DD)
                                : (A3 + (size_t)(e * 16 + (l - 16)) * DD);
    float4 v = ((const float4*)src)[col4];
    bf16x4 o = {(__bf16)v.x, (__bf16)v.y, (__bf16)v.z, (__bf16)v.w};
    ((bf16x4*)(dst + (size_t)j * DD))[col4] = o;
}

// A2 [E][R][F] fp32 -> A2t [E][F][R] bf16 (f-major, 16 contiguous bf16 per f)
__global__ __launch_bounds__(256) void cvt_A2t(const float* __restrict__ A2,
                                               __bf16* __restrict__ A2t) {
    int i = blockIdx.x * 256 + threadIdx.x;   // over E*RR*FF = 720896 exactly
    int f = i % FF;
    int r = (i / FF) % RR;
    int e = i / (FF * RR);
    A2t[((size_t)e * FF + f) * RR + r] = (__bf16)A2[i];
}

// ---------------------------------------------------------------------------
// Router: logits (fp32, output #2), top-2 renormalized weights per token
// ---------------------------------------------------------------------------
__global__ __launch_bounds__(256) void router_k(const float* __restrict__ x,
                                                const float* __restrict__ gw,
                                                float* __restrict__ logits,
                                                int* __restrict__ pair_e,
                                                float* __restrict__ pair_w) {
    int t = blockIdx.x * 4 + (threadIdx.x >> 6);
    int lane = threadIdx.x & 63;
    const float* xr = x + (size_t)t * DD;
    float acc[EE];
#pragma unroll
    for (int e = 0; e < EE; e++) acc[e] = 0.f;
    for (int d = lane; d < DD; d += 64) {
        float xv = xr[d];
#pragma unroll
        for (int e = 0; e < EE; e++) acc[e] += xv * gw[e * DD + d];
    }
#pragma unroll
    for (int off = 32; off > 0; off >>= 1) {
#pragma unroll
        for (int e = 0; e < EE; e++) acc[e] += __shfl_down(acc[e], off, 64);
    }
    if (lane == 0) {
        float mx = acc[0];
#pragma unroll
        for (int e = 1; e < EE; e++) mx = fmaxf(mx, acc[e]);
        float p[EE];
#pragma unroll
        for (int e = 0; e < EE; e++) p[e] = __expf(acc[e] - mx);
        int e0 = 0;
#pragma unroll
        for (int e = 1; e < EE; e++) if (p[e] > p[e0]) e0 = e;
        int e1 = (e0 == 0) ? 1 : 0;
#pragma unroll
        for (int e = 0; e < EE; e++) if (e != e0 && p[e] > p[e1]) e1 = e;
        float s = p[e0] + p[e1];
        pair_e[2 * t] = e0;     pair_e[2 * t + 1] = e1;
        pair_w[2 * t] = p[e0] / s; pair_w[2 * t + 1] = p[e1] / s;
#pragma unroll
        for (int e = 0; e < EE; e++) logits[(size_t)t * EE + e] = acc[e];
    }
}

// ---------------------------------------------------------------------------
// m97-style bf16 GEMM, B^T layout: C[M,N] = A[M,K] * B[N,K]^T
// ---------------------------------------------------------------------------
template <int OUT_BF16>
__global__ __launch_bounds__(256) void gemm_bt(const __bf16* __restrict__ A,
                                               const __bf16* __restrict__ B,
                                               void* __restrict__ Cv,
                                               int M, int N, int K) {
    __shared__ __align__(16) __bf16 As[128 * 32];
    __shared__ __align__(16) __bf16 Bs[128 * 32];
    const int tid  = threadIdx.x;
    const int wave = tid >> 6, lane = tid & 63;
    const int quad = lane >> 4, lrow = lane & 15;
    const int m0 = blockIdx.x * 128, n0 = blockIdx.y * 128;

    const int r0  = (tid << 4) >> 6;          // rows 0..63
    const int cb0 = (tid << 4) & 63;
    const size_t ldb = (size_t)K * 2;
    const char* gA0 = (const char*)A + (size_t)(m0 + r0) * ldb + cb0;
    const char* gA1 = (const char*)A + (size_t)(m0 + r0 + 64) * ldb + cb0;
    const char* gB0 = (const char*)B + (size_t)(n0 + r0) * ldb + cb0;
    const char* gB1 = (const char*)B + (size_t)(n0 + r0 + 64) * ldb + cb0;
    char* lA0 = ((char*)As) + (wave << 10);
    char* lA1 = ((char*)As) + 4096 + (wave << 10);
    char* lB0 = ((char*)Bs) + (wave << 10);
    char* lB1 = ((char*)Bs) + 4096 + (wave << 10);

    f32x4 acc[4][4] = {};

    const int abase = ((wave & 1) * 64 + lrow) * 32 + quad * 8;
    const int bbase = ((wave >> 1) * 64 + lrow) * 32 + quad * 8;

    const int KB = K * 2;   // bytes per row
    for (int kb = 0; kb < KB; kb += 64) {
        __syncthreads();
        __builtin_amdgcn_global_load_lds(AS1CAST((void*)(gA0 + kb)), AS3CAST(lA0), 16, 0, 0);
        __builtin_amdgcn_global_load_lds(AS1CAST((void*)(gA1 + kb)), AS3CAST(lA1), 16, 0, 0);
        __builtin_amdgcn_global_load_lds(AS1CAST((void*)(gB0 + kb)), AS3CAST(lB0), 16, 0, 0);
        __builtin_amdgcn_global_load_lds(AS1CAST((void*)(gB1 + kb)), AS3CAST(lB1), 16, 0, 0);
        __syncthreads();

        bf16x8 af[4], bfr[4];
#pragma unroll
        for (int i = 0; i < 4; i++) af[i]  = *(const bf16x8*)&As[abase + i * 16 * 32];
#pragma unroll
        for (int j = 0; j < 4; j++) bfr[j] = *(const bf16x8*)&Bs[bbase + j * 16 * 32];
#pragma unroll
        for (int i = 0; i < 4; i++)
#pragma unroll
            for (int j = 0; j < 4; j++)
                acc[i][j] = __builtin_amdgcn_mfma_f32_16x16x32_bf16(af[i], bfr[j], acc[i][j], 0, 0, 0);
    }

    const int wm = (wave & 1) * 64, wn = (wave >> 1) * 64;
#pragma unroll
    for (int i = 0; i < 4; i++) {
#pragma unroll
        for (int j = 0; j < 4; j++) {
#pragma unroll
            for (int r = 0; r < 4; r++) {
                int row = m0 + wm + i * 16 + quad * 4 + r;
                int col = n0 + wn + j * 16 + lrow;
                float v = acc[i][j][r];
                if (OUT_BF16) ((__bf16*)Cv)[(size_t)row * N + col] = (__bf16)v;
                else          ((float*)Cv)[(size_t)row * N + col] = v;
            }
        }
    }
}

// ---------------------------------------------------------------------------
// g_build_tok: one TOKEN per wave (both routed experts in one pass).
// u1 = base1 + ha1·B1[e][f,:], u3 = base3 + ha3·B3[e][f,:], g_e = silu(u1)*u3
// Writes the weight-combined row Gw[t][f] = w0*g0 + w1*g1 (bf16) so the
// down-projection GEMM runs once per token (not per pair).
// GA[2t+k][r] = w_k * sum_f g_k * A2t[e_k][f][r] (weights folded here).
// ---------------------------------------------------------------------------
__global__ __launch_bounds__(256) void g_build_tok(const __bf16* __restrict__ base,
                                                   const __bf16* __restrict__ B1t,
                                                   const __bf16* __restrict__ B3t,
                                                   const __bf16* __restrict__ A2t,
                                                   const int* __restrict__ pair_e,
                                                   const float* __restrict__ pair_w,
                                                   __bf16* __restrict__ G,
                                                   float* __restrict__ GA,
                                                   int t0) {
    const int wave = threadIdx.x >> 6, lane = threadIdx.x & 63;
    const int lt = blockIdx.x * 4 + wave;     // local token in chunk
    const int t = t0 + lt;                    // global token
    const int e0 = pair_e[2 * t], e1 = pair_e[2 * t + 1];
    const float w0 = pair_w[2 * t], w1 = pair_w[2 * t + 1];
    const __bf16* brow = base + (size_t)lt * NALL;

    // broadcast-load ha1/ha3 for both experts (same address all lanes)
    float ha1a[16], ha3a[16], ha1b[16], ha3b[16];
    {
        const bf16x8* pa = (const bf16x8*)(brow + 2 * FF + e0 * 32);
        const bf16x8* pb = (const bf16x8*)(brow + 2 * FF + e1 * 32);
        bf16x8 a0 = pa[0], a1 = pa[1], a2v = pa[2], a3v = pa[3];
        bf16x8 b0 = pb[0], b1v = pb[1], b2v = pb[2], b3v = pb[3];
#pragma unroll
        for (int r = 0; r < 8; r++) {
            ha1a[r] = (float)a0[r];  ha1a[8 + r] = (float)a1[r];
            ha3a[r] = (float)a2v[r]; ha3a[8 + r] = (float)a3v[r];
            ha1b[r] = (float)b0[r];  ha1b[8 + r] = (float)b1v[r];
            ha3b[r] = (float)b2v[r]; ha3b[8 + r] = (float)b3v[r];
        }
    }
    const __bf16* B1a = B1t + (size_t)e0 * FF * RR;
    const __bf16* B3a = B3t + (size_t)e0 * FF * RR;
    const __bf16* A2a = A2t + (size_t)e0 * FF * RR;
    const __bf16* B1b = B1t + (size_t)e1 * FF * RR;
    const __bf16* B3b = B3t + (size_t)e1 * FF * RR;
    const __bf16* A2b = A2t + (size_t)e1 * FF * RR;
    __bf16* Grow = G + (size_t)lt * FF;

    float ga0[16], ga1[16];
#pragma unroll
    for (int r = 0; r < 16; r++) { ga0[r] = 0.f; ga1[r] = 0.f; }

    for (int f = lane; f < FF; f += 64) {
        const size_t fo = (size_t)f * RR;
        const bf16x8* p;
        p = (const bf16x8*)(B1a + fo); bf16x8 b1l = p[0], b1h = p[1];
        p = (const bf16x8*)(B3a + fo); bf16x8 b3l = p[0], b3h = p[1];
        p = (const bf16x8*)(B1b + fo); bf16x8 c1l = p[0], c1h = p[1];
        p = (const bf16x8*)(B3b + fo); bf16x8 c3l = p[0], c3h = p[1];
        float bb1 = (float)brow[f], bb3 = (float)brow[FF + f];
        float u1a = bb1, u3a = bb3, u1b = bb1, u3b = bb3;
#pragma unroll
        for (int r = 0; r < 8; r++) {
            u1a += ha1a[r] * (float)b1l[r] + ha1a[8 + r] * (float)b1h[r];
            u3a += ha3a[r] * (float)b3l[r] + ha3a[8 + r] * (float)b3h[r];
            u1b += ha1b[r] * (float)c1l[r] + ha1b[8 + r] * (float)c1h[r];
            u3b += ha3b[r] * (float)c3l[r] + ha3b[8 + r] * (float)c3h[r];
        }
        float g0 = (u1a / (1.f + __expf(-u1a))) * u3a;
        float g1 = (u1b / (1.f + __expf(-u1b))) * u3b;
        Grow[f] = (__bf16)(w0 * g0 + w1 * g1);
        p = (const bf16x8*)(A2a + fo); bf16x8 a2l = p[0], a2h = p[1];
        p = (const bf16x8*)(A2b + fo); bf16x8 a4l = p[0], a4h = p[1];
#pragma unroll
        for (int r = 0; r < 8; r++) {
            ga0[r]     += g0 * (float)a2l[r];
            ga0[8 + r] += g0 * (float)a2h[r];
            ga1[r]     += g1 * (float)a4l[r];
            ga1[8 + r] += g1 * (float)a4h[r];
        }
    }
#pragma unroll
    for (int off = 32; off > 0; off >>= 1) {
#pragma unroll
        for (int r = 0; r < 16; r++) {
            ga0[r] += __shfl_down(ga0[r], off, 64);
            ga1[r] += __shfl_down(ga1[r], off, 64);
        }
    }
    if (lane == 0) {
#pragma unroll
        for (int r = 0; r < 16; r++) {
            GA[(size_t)(2 * t) * RR + r]     = w0 * ga0[r];
            GA[(size_t)(2 * t + 1) * RR + r] = w1 * ga1[r];
        }
    }
}

// ---------------------------------------------------------------------------
// out[t,d] = Y[lt,d] + GA[2t]·B2[e0][d,:] + GA[2t+1]·B2[e1][d,:]
// (routing weights already folded into Gw -> Y, and into GA)
// ---------------------------------------------------------------------------
__global__ __launch_bounds__(256) void combine_k(const float* __restrict__ Y,
                                                 const float* __restrict__ GA,
                                                 const float* __restrict__ B2,
                                                 const int* __restrict__ pair_e,
                                                 float* __restrict__ out,
                                                 int t0) {
    const int lt = blockIdx.x;
    const int t = t0 + lt;
    const int tid = threadIdx.x;
    __shared__ float g0[RR], g1[RR];
    if (tid < 16) g0[tid] = GA[(size_t)(2 * t) * RR + tid];
    else if (tid < 32) g1[tid - 16] = GA[(size_t)(2 * t + 1) * RR + (tid - 16)];
    __syncthreads();
    const int e0 = pair_e[2 * t], e1 = pair_e[2 * t + 1];
    const float* B2e0 = B2 + (size_t)e0 * DD * RR;
    const float* B2e1 = B2 + (size_t)e1 * DD * RR;
    for (int d = tid; d < DD; d += 256) {
        float l0 = 0.f, l1 = 0.f;
        const float4* b0 = (const float4*)(B2e0 + (size_t)d * RR);
        const float4* b1 = (const float4*)(B2e1 + (size_t)d * RR);
#pragma unroll
        for (int q = 0; q < 4; q++) {
            float4 v0 = b0[q], v1 = b1[q];
            l0 += g0[q * 4 + 0] * v0.x + g0[q * 4 + 1] * v0.y + g0[q * 4 + 2] * v0.z + g0[q * 4 + 3] * v0.w;
            l1 += g1[q * 4 + 0] * v1.x + g1[q * 4 + 1] * v1.y + g1[q * 4 + 2] * v1.z + g1[q * 4 + 3] * v1.w;
        }
        out[(size_t)t * DD + d] = Y[(size_t)lt * DD + d] + l0 + l1;
    }
}

// ---------------------------------------------------------------------------
extern "C" void kernel_launch(void* const* d_in, const int* in_sizes, int n_in,
                              void* d_out, int out_size, void* d_ws, size_t ws_size,
                              hipStream_t stream) {
    const float* x  = (const float*)d_in[0];
    const float* gw = (const float*)d_in[1];
    const float* W1 = (const float*)d_in[2];
    const float* W3 = (const float*)d_in[3];
    const float* W2 = (const float*)d_in[4];
    const float* A1 = (const float*)d_in[5];
    const float* B1 = (const float*)d_in[6];
    const float* A3 = (const float*)d_in[7];
    const float* B3 = (const float*)d_in[8];
    const float* A2 = (const float*)d_in[9];
    const float* B2 = (const float*)d_in[10];

    float* out    = (float*)d_out;                 // [T*D]
    float* logits = out + (size_t)TT * DD;         // [T*E]

    char* ws = (char*)d_ws;
    size_t off = 0;
    auto carve = [&](size_t bytes) {
        char* p = ws + off;
        off += (bytes + 255) & ~(size_t)255;
        return p;
    };
    auto pad = [](size_t b) { return (b + 255) & ~(size_t)255; };

    // ---- persistent buffers ----
    __bf16* W2b   = (__bf16*)carve((size_t)DD * FF * 2);        // 23.1 MB
    __bf16* B1b   = (__bf16*)carve((size_t)EE * FF * RR * 2);   // 1.44 MB
    __bf16* B3b   = (__bf16*)carve((size_t)EE * FF * RR * 2);   // 1.44 MB
    __bf16* A2t   = (__bf16*)carve((size_t)EE * FF * RR * 2);   // 1.44 MB
    float*  GA    = (float*)carve((size_t)NPAIR * RR * 4);      // 1 MB
    int*    pair_e = (int*)carve((size_t)NPAIR * 4);
    float*  pair_w = (float*)carve((size_t)NPAIR * 4);
    // W_all and h_bf are carved CONTIGUOUSLY so Y (67.1 MB fp32) can overlay
    // both once the last GEMM1 chunk has consumed them (80.7 MB available).
    __bf16* W_all = (__bf16*)carve((size_t)NALL * DD * 2);      // 47.2 MB  rows: W1|W3|A13
    __bf16* h_bf  = (__bf16*)carve((size_t)TT * DD * 2);        // 33.6 MB
    float*  Y_full = (float*)W_all;
    size_t base0 = off;

    // ---- mode/chunk selection (deterministic per call) ----
    int C = 0, full = 0;
    for (int c = 2048; c >= 256; c >>= 1) {
        size_t need = base0 + pad((size_t)TT * FF * 2) + pad((size_t)c * NALL * 2);
        if (need <= ws_size) { full = 1; C = c; break; }
    }
    __bf16* Gbuf; __bf16* base_c; float* Y_c = nullptr;
    if (full) {
        Gbuf   = (__bf16*)carve((size_t)TT * FF * 2);           // 92.3 MB: combined G, all tokens
        base_c = (__bf16*)carve((size_t)C * NALL * 2);
    } else {
        // fallback: per-chunk pipeline (combined-G still halves GEMM2 flops)
        C = 2048;
        while (C > 256) {
            size_t need = base0 + pad((size_t)C * NALL * 2) + pad((size_t)C * FF * 2);
            if (need <= ws_size) break;
            C >>= 1;
        }
        base_c = (__bf16*)carve((size_t)C * NALL * 2);
        Gbuf   = (__bf16*)carve((size_t)C * FF * 2);
        Y_c    = (float*)base_c;     // C*D*4 <= C*NALL*2, base dead before GEMM2
    }

    // 1. converts (weights + full activation, once)
    cvt_f32_bf16<<<2048, 256, 0, stream>>>(x, h_bf, TT * DD / 4);
    cvt_f32_bf16<<<1024, 256, 0, stream>>>(W1, W_all, FF * DD / 4);
    cvt_f32_bf16<<<1024, 256, 0, stream>>>(W3, W_all + (size_t)FF * DD, FF * DD / 4);
    cvt_f32_bf16<<<1024, 256, 0, stream>>>(W2, W2b, DD * FF / 4);
    cvt_A13<<<512, 256, 0, stream>>>(A1, A3, W_all + (size_t)2 * FF * DD);
    cvt_f32_bf16<<<512, 256, 0, stream>>>(B1, B1b, EE * FF * RR / 4);
    cvt_f32_bf16<<<512, 256, 0, stream>>>(B3, B3b, EE * FF * RR / 4);
    cvt_A2t<<<EE * RR * FF / 256, 256, 0, stream>>>(A2, A2t);

    // 2. router (fp32) — writes logits output + pair routing
    router_k<<<TT / 4, 256, 0, stream>>>(x, gw, logits, pair_e, pair_w);

    // 3-4. chunked: up-projections + gate build (weight-combined G)
    for (int t0 = 0; t0 < TT; t0 += C) {
        gemm_bt<1><<<dim3(C / 128, NALL / 128), 256, 0, stream>>>(
            h_bf + (size_t)t0 * DD, W_all, base_c, C, NALL, DD);
        __bf16* Gp = full ? (Gbuf + (size_t)t0 * FF) : Gbuf;
        g_build_tok<<<C / 4, 256, 0, stream>>>(base_c, B1b, B3b, A2t, pair_e, pair_w, Gp, GA, t0);
        if (!full) {
            gemm_bt<0><<<dim3(C / 128, DD / 128), 256, 0, stream>>>(
                Gbuf, W2b, Y_c, C, DD, FF);
            combine_k<<<C, 256, 0, stream>>>(Y_c, GA, B2, pair_e, out, t0);
        }
    }

    // 5-6. one-shot down-projection over all tokens (grid 64x16 = 4 blocks/CU)
    if (full) {
        gemm_bt<0><<<dim3(TT / 128, DD / 128), 256, 0, stream>>>(
            Gbuf, W2b, Y_full, TT, DD, FF);
        combine_k<<<TT, 256, 0, stream>>>(Y_full, GA, B2, pair_e, out, 0);
    }
}

// Round 3
// 1499.582 us; speedup vs baseline: 1.2761x; 1.0886x over previous
//
#include <hip/hip_runtime.h>
#include <hip/hip_bf16.h>
#include <stdint.h>

// Problem constants
#define TT   8192      // tokens = B*S
#define DD   2048      // d_model
#define FF   5632      // ffn hidden
#define EE   8         // experts
#define RR   16        // lora rank
#define NALL 11520     // F + F + E*2R = 5632+5632+256
#define NPAIR 16384    // T * TOPK

typedef float  f32x4  __attribute__((ext_vector_type(4)));
typedef __bf16 bf16x8 __attribute__((ext_vector_type(8)));
typedef __bf16 bf16x4 __attribute__((ext_vector_type(4)));

#define AS1CAST(p) ((__attribute__((address_space(1))) void*)(p))
#define AS3CAST(p) ((__attribute__((address_space(3))) void*)(p))

// ---------------------------------------------------------------------------
// f32 -> bf16 convert (float4 vectorized, grid-stride)
// ---------------------------------------------------------------------------
__global__ __launch_bounds__(256) void cvt_f32_bf16(const float* __restrict__ src,
                                                    __bf16* __restrict__ dst, int n4) {
    int stride = gridDim.x * 256;
    for (int i = blockIdx.x * 256 + threadIdx.x; i < n4; i += stride) {
        float4 v = ((const float4*)src)[i];
        bf16x4 o = {(__bf16)v.x, (__bf16)v.y, (__bf16)v.z, (__bf16)v.w};
        ((bf16x4*)dst)[i] = o;
    }
}

// Gather-convert A1/A3 into stacked rows [256][D]: row j=e*32+l, l<16 -> A1[e][l], else A3[e][l-16]
__global__ __launch_bounds__(256) void cvt_A13(const float* __restrict__ A1,
                                               const float* __restrict__ A3,
                                               __bf16* __restrict__ dst) {
    int i = blockIdx.x * 256 + threadIdx.x;   // [0, 256*512)
    int col4 = i & 511;                       // D/4 = 512
    int j = i >> 9;                           // row 0..255
    int e = j >> 5, l = j & 31;
    const float* src = (l < 16) ? (A1 + (size_t)(e * 16 + l) * DD)
                                : (A3 + (size_t)(e * 16 + (l - 16)) * DD);
    float4 v = ((const float4*)src)[col4];
    bf16x4 o = {(__bf16)v.x, (__bf16)v.y, (__bf16)v.z, (__bf16)v.w};
    ((bf16x4*)(dst + (size_t)j * DD))[col4] = o;
}

// A2 [E][R][F] fp32 -> A2t [E][F][R] bf16 (f-major, 16 contiguous bf16 per f)
__global__ __launch_bounds__(256) void cvt_A2t(const float* __restrict__ A2,
                                               __bf16* __restrict__ A2t) {
    int i = blockIdx.x * 256 + threadIdx.x;   // over E*RR*FF = 720896 exactly
    int f = i % FF;
    int r = (i / FF) % RR;
    int e = i / (FF * RR);
    A2t[((size_t)e * FF + f) * RR + r] = (__bf16)A2[i];
}

// ---------------------------------------------------------------------------
// Router: logits (fp32, output #2), top-2 renormalized weights per token
// ---------------------------------------------------------------------------
__global__ __launch_bounds__(256) void router_k(const float* __restrict__ x,
                                                const float* __restrict__ gw,
                                                float* __restrict__ logits,
                                                int* __restrict__ pair_e,
                                                float* __restrict__ pair_w) {
    int t = blockIdx.x * 4 + (threadIdx.x >> 6);
    int lane = threadIdx.x & 63;
    const float* xr = x + (size_t)t * DD;
    float acc[EE];
#pragma unroll
    for (int e = 0; e < EE; e++) acc[e] = 0.f;
    for (int d = lane; d < DD; d += 64) {
        float xv = xr[d];
#pragma unroll
        for (int e = 0; e < EE; e++) acc[e] += xv * gw[e * DD + d];
    }
#pragma unroll
    for (int off = 32; off > 0; off >>= 1) {
#pragma unroll
        for (int e = 0; e < EE; e++) acc[e] += __shfl_down(acc[e], off, 64);
    }
    if (lane == 0) {
        float mx = acc[0];
#pragma unroll
        for (int e = 1; e < EE; e++) mx = fmaxf(mx, acc[e]);
        float p[EE];
#pragma unroll
        for (int e = 0; e < EE; e++) p[e] = __expf(acc[e] - mx);
        int e0 = 0;
#pragma unroll
        for (int e = 1; e < EE; e++) if (p[e] > p[e0]) e0 = e;
        int e1 = (e0 == 0) ? 1 : 0;
#pragma unroll
        for (int e = 0; e < EE; e++) if (e != e0 && p[e] > p[e1]) e1 = e;
        float s = p[e0] + p[e1];
        pair_e[2 * t] = e0;     pair_e[2 * t + 1] = e1;
        pair_w[2 * t] = p[e0] / s; pair_w[2 * t + 1] = p[e1] / s;
#pragma unroll
        for (int e = 0; e < EE; e++) logits[(size_t)t * EE + e] = acc[e];
    }
}

// ---------------------------------------------------------------------------
// 256x256-tile 8-phase bf16 GEMM (T1+T2+T3+T4+T5), B^T layout:
// C[M,N] = A[M,K] * B[N,K]^T.  M,N multiples of 256; K multiple of 128.
// 512 threads = 8 waves (2M x 4N); per-wave output 128x64; BK=64; LDS 128 KiB.
// st_16x32 swizzle: byte ^= ((row>>2)&1)<<5, applied as inverse-swizzled
// GLOBAL source (global_load_lds writes linearly) + swizzled ds_read.
// Counted vmcnt(4) once per K-tile (phase 4 of each DO4); epilogue drains to 0.
// launch_bounds(512,2): force <=256 VGPR so the 8-wave workgroup is schedulable.
// ---------------------------------------------------------------------------
template <int OUT_BF16>
__global__ __launch_bounds__(512, 2) void gemm256(const __bf16* __restrict__ A,
                                                  const __bf16* __restrict__ B,
                                                  void* __restrict__ Cv,
                                                  int M, int N, int K) {
    __shared__ __align__(16) __bf16 lds[8][8192];   // [buf*4 + mat*2 + half][128*64]
    char* const sbase = (char*)&lds[0][0];
    const int tid = threadIdx.x;
    const int w = tid >> 6, lane = tid & 63;
    const int lrow = lane & 15, lq = lane >> 4;
    const int wr = w >> 2, wc = w & 3;

    // bijective XCD swizzle (m204): each XCD gets a contiguous chunk of tiles
    const int gx = gridDim.x;
    const int nwg = gx * gridDim.y;
    const int orig = blockIdx.x + blockIdx.y * gx;
    const int q8 = nwg >> 3, r8 = nwg & 7;
    const int xcd = orig & 7, sid = orig >> 3;
    const int nid = (xcd < r8 ? xcd * (q8 + 1) : r8 * (q8 + 1) + (xcd - r8) * q8) + sid;
    const int m0 = (nid % gx) * 256;
    const int n0 = (nid / gx) * 256;

    const size_t ldb = (size_t)K * 2;               // bytes per row
    // staging geometry: wave w, instr q covers LDS seg rows w*16+q*8 .. +8;
    // lane writes 16B at row w*16 + q*8 + (lane>>3), col-byte (lane&7)*16.
    const int rq0 = w * 16 + (lane >> 3);
    const int cbs = ((lane & 7) * 16) ^ (((rq0 >> 2) & 1) << 5);  // inverse-swz source col
    const char* gA0 = (const char*)A + (size_t)(m0 + rq0) * ldb + cbs;   // A half0
    const char* gA1 = gA0 + (size_t)128 * ldb;                            // A half1
    const char* gB0 = (const char*)B + (size_t)(n0 + rq0) * ldb + cbs;
    const char* gB1 = gB0 + (size_t)128 * ldb;
    const int wseg = w * 2048;

    // read geometry (swizzle bit is thread-constant: row bit2 == lrow bit2)
    const int sb = ((lrow >> 2) & 1) << 5;
    const int aoff = lrow * 128 + ((lq * 16) ^ sb);
    const int boff = ((wc & 1) * 64 + lrow) * 128 + ((lq * 16) ^ sb);
    const int abuf = wr;             // A half this wave reads
    const int bbuf = 2 + (wc >> 1);  // B half this wave reads

    f32x4 acc[8][4] = {};
    bf16x8 aR[4][2], aS[4][2], bR[2][2], bS[2][2];

#define GLDS(gp, lo) __builtin_amdgcn_global_load_lds(AS1CAST((void*)(gp)), AS3CAST(sbase + (lo)), 16, 0, 0)
#define STAGEM(gp, bufmh) do { const char* _g = (gp); \
        GLDS(_g, (bufmh) * 16384 + wseg); \
        GLDS(_g + 8 * ldb, (bufmh) * 16384 + wseg + 1024); } while (0)
#define LDAf(c, i, ks) (*(const bf16x8*)(sbase + ((c) * 4 + abuf) * 16384 + aoff + (i) * 2048 + (ks) * 64))
#define LDBf(c, j, ks) (*(const bf16x8*)(sbase + ((c) * 4 + bbuf) * 16384 + boff + (j) * 2048 + (ks) * 64))
#define MM(i, j, fa, fb) acc[i][j] = __builtin_amdgcn_mfma_f32_16x16x32_bf16(fa, fb, acc[i][j], 0, 0, 0)
#define PH_MID() do { __builtin_amdgcn_s_barrier(); \
        asm volatile("s_waitcnt lgkmcnt(0)" ::: "memory"); \
        __builtin_amdgcn_sched_barrier(0); \
        __builtin_amdgcn_s_setprio(1); } while (0)
#define PH_END() do { __builtin_amdgcn_s_setprio(0); \
        __builtin_amdgcn_s_barrier(); } while (0)

// 4 phases consuming buf c; stages: B halves of tile kBC -> buf c^1,
// then A halves of tile kAC -> buf c.  vmcnt(4) after 4th stage.
#define DO4(c, kBC, kAC) do { \
    _Pragma("unroll") for (int i = 0; i < 4; i++) { aR[i][0] = LDAf(c, i, 0); aR[i][1] = LDAf(c, i, 1); } \
    _Pragma("unroll") for (int j = 0; j < 2; j++) { bR[j][0] = LDBf(c, j, 0); bR[j][1] = LDBf(c, j, 1); } \
    STAGEM(gB0 + (size_t)(kBC) * 128, ((c) ^ 1) * 4 + 2); \
    PH_MID(); \
    _Pragma("unroll") for (int i = 0; i < 4; i++) \
    _Pragma("unroll") for (int j = 0; j < 2; j++) { MM(i, j, aR[i][0], bR[j][0]); MM(i, j, aR[i][1], bR[j][1]); } \
    PH_END(); \
    _Pragma("unroll") for (int i = 0; i < 4; i++) { aS[i][0] = LDAf(c, 4 + i, 0); aS[i][1] = LDAf(c, 4 + i, 1); } \
    STAGEM(gB1 + (size_t)(kBC) * 128, ((c) ^ 1) * 4 + 3); \
    PH_MID(); \
    _Pragma("unroll") for (int i = 0; i < 4; i++) \
    _Pragma("unroll") for (int j = 0; j < 2; j++) { MM(4 + i, j, aS[i][0], bR[j][0]); MM(4 + i, j, aS[i][1], bR[j][1]); } \
    PH_END(); \
    _Pragma("unroll") for (int j = 0; j < 2; j++) { bS[j][0] = LDBf(c, 2 + j, 0); bS[j][1] = LDBf(c, 2 + j, 1); } \
    STAGEM(gA0 + (size_t)(kAC) * 128, (c) * 4 + 0); \
    PH_MID(); \
    _Pragma("unroll") for (int i = 0; i < 4; i++) \
    _Pragma("unroll") for (int j = 0; j < 2; j++) { MM(i, 2 + j, aR[i][0], bS[j][0]); MM(i, 2 + j, aR[i][1], bS[j][1]); } \
    PH_END(); \
    STAGEM(gA1 + (size_t)(kAC) * 128, (c) * 4 + 1); \
    asm volatile("s_waitcnt vmcnt(4)" ::: "memory"); \
    PH_MID(); \
    _Pragma("unroll") for (int i = 0; i < 4; i++) \
    _Pragma("unroll") for (int j = 0; j < 2; j++) { MM(4 + i, 2 + j, aS[i][0], bS[j][0]); MM(4 + i, 2 + j, aS[i][1], bS[j][1]); } \
    PH_END(); \
} while (0)

    const int NT = K >> 6;        // 64-wide K-tiles (even: K % 128 == 0)
    const int NI = NT >> 1;

    // prologue: buf0 <- kt0 (A0,A1,B0,B1); buf1 <- kt1 (A halves). Keep last 2 in flight.
    STAGEM(gA0, 0); STAGEM(gA1, 1); STAGEM(gB0, 2); STAGEM(gB1, 3);
    STAGEM(gA0 + 128, 4); STAGEM(gA1 + 128, 5);
    asm volatile("s_waitcnt vmcnt(4)" ::: "memory");
    __builtin_amdgcn_s_barrier();

    for (int it = 0; it < NI; it++) {
        int k2 = 2 * it + 2; if (k2 > NT - 1) k2 = NT - 1;   // clamped tail prefetch
        int k3 = 2 * it + 3; if (k3 > NT - 1) k3 = NT - 1;
        DO4(0, 2 * it + 1, k2);
        DO4(1, k2, k3);
    }

    // drain all in-flight global_load_lds before workgroup can retire
    // (pending LDS-targeting DMA past endpgm corrupts successor workgroups)
    asm volatile("s_waitcnt vmcnt(0)" ::: "memory");

#undef DO4
#undef PH_END
#undef PH_MID
#undef MM
#undef LDBf
#undef LDAf
#undef STAGEM
#undef GLDS

    // epilogue: C/D layout col=lane&15, row=(lane>>4)*4+reg (m89-verified)
#pragma unroll
    for (int i = 0; i < 8; i++)
#pragma unroll
        for (int j = 0; j < 4; j++)
#pragma unroll
            for (int r = 0; r < 4; r++) {
                int row = m0 + wr * 128 + i * 16 + lq * 4 + r;
                int col = n0 + wc * 64 + j * 16 + lrow;
                float v = acc[i][j][r];
                if (OUT_BF16) ((__bf16*)Cv)[(size_t)row * N + col] = (__bf16)v;
                else          ((float*)Cv)[(size_t)row * N + col] = v;
            }
}

// ---------------------------------------------------------------------------
// g_build_tok: one TOKEN per wave (both routed experts in one pass).
// Writes Gw[t][f] = w0*g0 + w1*g1 (bf16); GA[2t+k][r] = w_k * sum_f g_k*A2t.
// ---------------------------------------------------------------------------
__global__ __launch_bounds__(256) void g_build_tok(const __bf16* __restrict__ base,
                                                   const __bf16* __restrict__ B1t,
                                                   const __bf16* __restrict__ B3t,
                                                   const __bf16* __restrict__ A2t,
                                                   const int* __restrict__ pair_e,
                                                   const float* __restrict__ pair_w,
                                                   __bf16* __restrict__ G,
                                                   float* __restrict__ GA,
                                                   int t0) {
    const int wave = threadIdx.x >> 6, lane = threadIdx.x & 63;
    const int lt = blockIdx.x * 4 + wave;     // local token in chunk
    const int t = t0 + lt;                    // global token
    const int e0 = pair_e[2 * t], e1 = pair_e[2 * t + 1];
    const float w0 = pair_w[2 * t], w1 = pair_w[2 * t + 1];
    const __bf16* brow = base + (size_t)lt * NALL;

    float ha1a[16], ha3a[16], ha1b[16], ha3b[16];
    {
        const bf16x8* pa = (const bf16x8*)(brow + 2 * FF + e0 * 32);
        const bf16x8* pb = (const bf16x8*)(brow + 2 * FF + e1 * 32);
        bf16x8 a0 = pa[0], a1 = pa[1], a2v = pa[2], a3v = pa[3];
        bf16x8 b0 = pb[0], b1v = pb[1], b2v = pb[2], b3v = pb[3];
#pragma unroll
        for (int r = 0; r < 8; r++) {
            ha1a[r] = (float)a0[r];  ha1a[8 + r] = (float)a1[r];
            ha3a[r] = (float)a2v[r]; ha3a[8 + r] = (float)a3v[r];
            ha1b[r] = (float)b0[r];  ha1b[8 + r] = (float)b1v[r];
            ha3b[r] = (float)b2v[r]; ha3b[8 + r] = (float)b3v[r];
        }
    }
    const __bf16* B1a = B1t + (size_t)e0 * FF * RR;
    const __bf16* B3a = B3t + (size_t)e0 * FF * RR;
    const __bf16* A2a = A2t + (size_t)e0 * FF * RR;
    const __bf16* B1b = B1t + (size_t)e1 * FF * RR;
    const __bf16* B3b = B3t + (size_t)e1 * FF * RR;
    const __bf16* A2b = A2t + (size_t)e1 * FF * RR;
    __bf16* Grow = G + (size_t)lt * FF;

    float ga0[16], ga1[16];
#pragma unroll
    for (int r = 0; r < 16; r++) { ga0[r] = 0.f; ga1[r] = 0.f; }

    for (int f = lane; f < FF; f += 64) {
        const size_t fo = (size_t)f * RR;
        const bf16x8* p;
        p = (const bf16x8*)(B1a + fo); bf16x8 b1l = p[0], b1h = p[1];
        p = (const bf16x8*)(B3a + fo); bf16x8 b3l = p[0], b3h = p[1];
        p = (const bf16x8*)(B1b + fo); bf16x8 c1l = p[0], c1h = p[1];
        p = (const bf16x8*)(B3b + fo); bf16x8 c3l = p[0], c3h = p[1];
        float bb1 = (float)brow[f], bb3 = (float)brow[FF + f];
        float u1a = bb1, u3a = bb3, u1b = bb1, u3b = bb3;
#pragma unroll
        for (int r = 0; r < 8; r++) {
            u1a += ha1a[r] * (float)b1l[r] + ha1a[8 + r] * (float)b1h[r];
            u3a += ha3a[r] * (float)b3l[r] + ha3a[8 + r] * (float)b3h[r];
            u1b += ha1b[r] * (float)c1l[r] + ha1b[8 + r] * (float)c1h[r];
            u3b += ha3b[r] * (float)c3l[r] + ha3b[8 + r] * (float)c3h[r];
        }
        float g0 = (u1a / (1.f + __expf(-u1a))) * u3a;
        float g1 = (u1b / (1.f + __expf(-u1b))) * u3b;
        Grow[f] = (__bf16)(w0 * g0 + w1 * g1);
        p = (const bf16x8*)(A2a + fo); bf16x8 a2l = p[0], a2h = p[1];
        p = (const bf16x8*)(A2b + fo); bf16x8 a4l = p[0], a4h = p[1];
#pragma unroll
        for (int r = 0; r < 8; r++) {
            ga0[r]     += g0 * (float)a2l[r];
            ga0[8 + r] += g0 * (float)a2h[r];
            ga1[r]     += g1 * (float)a4l[r];
            ga1[8 + r] += g1 * (float)a4h[r];
        }
    }
#pragma unroll
    for (int off = 32; off > 0; off >>= 1) {
#pragma unroll
        for (int r = 0; r < 16; r++) {
            ga0[r] += __shfl_down(ga0[r], off, 64);
            ga1[r] += __shfl_down(ga1[r], off, 64);
        }
    }
    if (lane == 0) {
#pragma unroll
        for (int r = 0; r < 16; r++) {
            GA[(size_t)(2 * t) * RR + r]     = w0 * ga0[r];
            GA[(size_t)(2 * t + 1) * RR + r] = w1 * ga1[r];
        }
    }
}

// ---------------------------------------------------------------------------
// out[t,d] = Y[lt,d] + GA[2t]·B2[e0][d,:] + GA[2t+1]·B2[e1][d,:]
// ---------------------------------------------------------------------------
__global__ __launch_bounds__(256) void combine_k(const float* __restrict__ Y,
                                                 const float* __restrict__ GA,
                                                 const float* __restrict__ B2,
                                                 const int* __restrict__ pair_e,
                                                 float* __restrict__ out,
                                                 int t0) {
    const int lt = blockIdx.x;
    const int t = t0 + lt;
    const int tid = threadIdx.x;
    __shared__ float g0[RR], g1[RR];
    if (tid < 16) g0[tid] = GA[(size_t)(2 * t) * RR + tid];
    else if (tid < 32) g1[tid - 16] = GA[(size_t)(2 * t + 1) * RR + (tid - 16)];
    __syncthreads();
    const int e0 = pair_e[2 * t], e1 = pair_e[2 * t + 1];
    const float* B2e0 = B2 + (size_t)e0 * DD * RR;
    const float* B2e1 = B2 + (size_t)e1 * DD * RR;
    for (int d = tid; d < DD; d += 256) {
        float l0 = 0.f, l1 = 0.f;
        const float4* b0 = (const float4*)(B2e0 + (size_t)d * RR);
        const float4* b1 = (const float4*)(B2e1 + (size_t)d * RR);
#pragma unroll
        for (int q = 0; q < 4; q++) {
            float4 v0 = b0[q], v1 = b1[q];
            l0 += g0[q * 4 + 0] * v0.x + g0[q * 4 + 1] * v0.y + g0[q * 4 + 2] * v0.z + g0[q * 4 + 3] * v0.w;
            l1 += g1[q * 4 + 0] * v1.x + g1[q * 4 + 1] * v1.y + g1[q * 4 + 2] * v1.z + g1[q * 4 + 3] * v1.w;
        }
        out[(size_t)t * DD + d] = Y[(size_t)lt * DD + d] + l0 + l1;
    }
}

// ---------------------------------------------------------------------------
extern "C" void kernel_launch(void* const* d_in, const int* in_sizes, int n_in,
                              void* d_out, int out_size, void* d_ws, size_t ws_size,
                              hipStream_t stream) {
    const float* x  = (const float*)d_in[0];
    const float* gw = (const float*)d_in[1];
    const float* W1 = (const float*)d_in[2];
    const float* W3 = (const float*)d_in[3];
    const float* W2 = (const float*)d_in[4];
    const float* A1 = (const float*)d_in[5];
    const float* B1 = (const float*)d_in[6];
    const float* A3 = (const float*)d_in[7];
    const float* B3 = (const float*)d_in[8];
    const float* A2 = (const float*)d_in[9];
    const float* B2 = (const float*)d_in[10];

    float* out    = (float*)d_out;                 // [T*D]
    float* logits = out + (size_t)TT * DD;         // [T*E]

    char* ws = (char*)d_ws;
    size_t off = 0;
    auto carve = [&](size_t bytes) {
        char* p = ws + off;
        off += (bytes + 255) & ~(size_t)255;
        return p;
    };
    auto pad = [](size_t b) { return (b + 255) & ~(size_t)255; };

    // ---- persistent buffers ----
    __bf16* W2b   = (__bf16*)carve((size_t)DD * FF * 2);        // 23.1 MB
    __bf16* B1b   = (__bf16*)carve((size_t)EE * FF * RR * 2);   // 1.44 MB
    __bf16* B3b   = (__bf16*)carve((size_t)EE * FF * RR * 2);   // 1.44 MB
    __bf16* A2t   = (__bf16*)carve((size_t)EE * FF * RR * 2);   // 1.44 MB
    float*  GA    = (float*)carve((size_t)NPAIR * RR * 4);      // 1 MB
    int*    pair_e = (int*)carve((size_t)NPAIR * 4);
    float*  pair_w = (float*)carve((size_t)NPAIR * 4);
    // W_all and h_bf carved CONTIGUOUSLY so Y (67.1 MB fp32) overlays both
    // once the last GEMM1 chunk has consumed them (80.7 MB available).
    __bf16* W_all = (__bf16*)carve((size_t)NALL * DD * 2);      // 47.2 MB  rows: W1|W3|A13
    __bf16* h_bf  = (__bf16*)carve((size_t)TT * DD * 2);        // 33.6 MB
    float*  Y_full = (float*)W_all;
    size_t base0 = off;

    // ---- mode/chunk selection (deterministic per call) ----
    int C = 0, full = 0;
    {
        const int cand[6] = {8192, 4096, 2048, 1024, 512, 256};
        for (int ci = 0; ci < 6; ci++) {
            int c = cand[ci];
            size_t need = base0 + pad((size_t)TT * FF * 2) + pad((size_t)c * NALL * 2);
            if (need <= ws_size) { full = 1; C = c; break; }
        }
    }
    __bf16* Gbuf; __bf16* base_c; float* Y_c = nullptr;
    if (full) {
        Gbuf   = (__bf16*)carve((size_t)TT * FF * 2);           // 92.3 MB: combined G, all tokens
        base_c = (__bf16*)carve((size_t)C * NALL * 2);
    } else {
        // fallback: per-chunk pipeline (combined-G still halves GEMM2 flops)
        C = 2048;
        while (C > 256) {
            size_t need = base0 + pad((size_t)C * NALL * 2) + pad((size_t)C * FF * 2);
            if (need <= ws_size) break;
            C >>= 1;
        }
        base_c = (__bf16*)carve((size_t)C * NALL * 2);
        Gbuf   = (__bf16*)carve((size_t)C * FF * 2);
        Y_c    = (float*)base_c;     // C*D*4 <= C*NALL*2, base dead by then
    }

    // 1. converts (weights + full activation, once)
    cvt_f32_bf16<<<2048, 256, 0, stream>>>(x, h_bf, TT * DD / 4);
    cvt_f32_bf16<<<1024, 256, 0, stream>>>(W1, W_all, FF * DD / 4);
    cvt_f32_bf16<<<1024, 256, 0, stream>>>(W3, W_all + (size_t)FF * DD, FF * DD / 4);
    cvt_f32_bf16<<<1024, 256, 0, stream>>>(W2, W2b, DD * FF / 4);
    cvt_A13<<<512, 256, 0, stream>>>(A1, A3, W_all + (size_t)2 * FF * DD);
    cvt_f32_bf16<<<512, 256, 0, stream>>>(B1, B1b, EE * FF * RR / 4);
    cvt_f32_bf16<<<512, 256, 0, stream>>>(B3, B3b, EE * FF * RR / 4);
    cvt_A2t<<<EE * RR * FF / 256, 256, 0, stream>>>(A2, A2t);

    // 2. router (fp32) — writes logits output + pair routing
    router_k<<<TT / 4, 256, 0, stream>>>(x, gw, logits, pair_e, pair_w);

    // 3-4. up-projection + gate build (weight-combined G)
    for (int t0 = 0; t0 < TT; t0 += C) {
        gemm256<1><<<dim3(C / 256, NALL / 256), 512, 0, stream>>>(
            h_bf + (size_t)t0 * DD, W_all, base_c, C, NALL, DD);
        __bf16* Gp = full ? (Gbuf + (size_t)t0 * FF) : Gbuf;
        g_build_tok<<<C / 4, 256, 0, stream>>>(base_c, B1b, B3b, A2t, pair_e, pair_w, Gp, GA, t0);
        if (!full) {
            gemm256<0><<<dim3(C / 256, DD / 256), 512, 0, stream>>>(
                Gbuf, W2b, Y_c, C, DD, FF);
            combine_k<<<C, 256, 0, stream>>>(Y_c, GA, B2, pair_e, out, t0);
        }
    }

    // 5-6. one-shot down-projection over all tokens
    if (full) {
        gemm256<0><<<dim3(TT / 256, DD / 256), 512, 0, stream>>>(
            Gbuf, W2b, Y_full, TT, DD, FF);
        combine_k<<<TT, 256, 0, stream>>>(Y_full, GA, B2, pair_e, out, 0);
    }
}